// Round 3
// baseline (242.009 us; speedup 1.0000x reference)
//
#include <hip/hip_runtime.h>
#include <hip/hip_bf16.h>

// SirenLinear: out[b,r] = sum_c x[b,c] * W[r,c] + bias[r]
//   W[r,c] = b3 + h2 . W3,  h2 = sin(30*(W2 h1 + b2)),  h1 = sin(30*(W1 e + b1))
//
// Round-9 changes (post-mortem r1/r2: fused cast+siren = 67us, insensitive to
// block distribution -> shared-throughput-bound; trans pipe (134M sins) is the
// prime suspect; fusion also wrecked cast streaming, 545 GB/s):
//  * DE-FUSED: cast is a pure 8192-block streaming kernel again (~6 TB/s).
//  * Layer-1 sins eliminated via sin(a+b) identity: tables kernel stores
//    {sin,cos} float2 tables for rows/cols (262k sins, ~free); each h1 is now
//    mul+fma instead of add+v_sin. Halves total trans work (64/point left).
//  * siren standalone, 2048 blocks = 8 blocks/CU.
//  * gemm keeps round-7 double-buffered LDS (1 barrier/K-tile, ~30us).

typedef __attribute__((ext_vector_type(8))) short bf16x8;
typedef __attribute__((ext_vector_type(4))) float f32x4;

#define SIN_SCALE 4.77464829275686f   // 30 / (2*pi)

__device__ __forceinline__ unsigned short f2bf(float f) {
    union { float f; unsigned u; } v; v.f = f;
    unsigned r = v.u + 0x7fffu + ((v.u >> 16) & 1u);   // RNE
    return (unsigned short)(r >> 16);
}

// pack 2 floats -> 2 bf16 by truncation (cheap; RNE kept for final store)
__device__ __forceinline__ unsigned pktrunc(float a, float b) {
    union { float f; unsigned u; } x, y; x.f = a; y.f = b;
    return (x.u >> 16) | (y.u & 0xffff0000u);
}

// sin/cos(2*pi*x) -- raw v_sin/v_cos, valid |x| <= 256 revs (here |x| <= ~14)
__device__ __forceinline__ float sinrev(float x) {
    return __builtin_amdgcn_sinf(x);
}
__device__ __forceinline__ float cosrev(float x) {
    return __builtin_amdgcn_cosf(x);
}

// butterfly add over lane^m (bitmode ds_swizzle)
template <int OFF>
__device__ __forceinline__ float swz_add(float v) {
    return v + __int_as_float(__builtin_amdgcn_ds_swizzle(__float_as_int(v), OFF));
}

__device__ __forceinline__ void async_ld16(const void* g, void* l) {
    __builtin_amdgcn_global_load_lds(
        (__attribute__((address_space(1))) void*)g,
        (__attribute__((address_space(3))) void*)l, 16, 0, 0);
}

// ---------------- stage 0: layer-1 separable sin/cos tables ----------------
// zrow[r][j] = S*(W1[j,:].e(r,0)+b1[j]);  zcol[c][j] = S*(W1[j,:].(e(0,c)-e(0,0)))
// SCrow[r][j] = {sin(2pi zrow), cos(2pi zrow)};  SCcol likewise.
// Then h1 = sin(2pi(zr+zc)) = sr*cc + cr*sc  -- no device sin in layer 1.
__global__ __launch_bounds__(256) void tables_kernel(
        const float* __restrict__ ec,
        const float* __restrict__ W1, const float* __restrict__ b1,
        float2* __restrict__ SCrow, float2* __restrict__ SCcol) {
    int idx = blockIdx.x * 256 + threadIdx.x;    // 0..131071
    int j = idx & 63;
    int t = idx >> 6;                            // 0..2047
    const float* wr = W1 + j * 18;
    if (t < 1024) {
        const float* pe = ec + (long)t * 1024 * 18;   // point (r=t, c=0)
        float z = b1[j];
        #pragma unroll
        for (int i = 0; i < 18; ++i) z += wr[i] * pe[i];
        z *= SIN_SCALE;
        SCrow[t * 64 + j] = make_float2(sinrev(z), cosrev(z));
    } else {
        int c = t - 1024;
        const float* pe = ec + (long)c * 18;          // point (r=0, c)
        float z = 0.f;
        #pragma unroll
        for (int i = 0; i < 18; ++i) z += wr[i] * (pe[i] - ec[i]);
        z *= SIN_SCALE;
        SCcol[c * 64 + j] = make_float2(sinrev(z), cosrev(z));
    }
}

// ---------------- stage 1: x cast -> bf16 (pure streaming) ----------------
__global__ __launch_bounds__(256) void cast_kernel(
        const float4* __restrict__ x, unsigned short* __restrict__ xb) {
    long i = (long)blockIdx.x * 256 + threadIdx.x;
    float4 v = x[i];
    ushort4 o;
    o.x = f2bf(v.x); o.y = f2bf(v.y); o.z = f2bf(v.z); o.w = f2bf(v.w);
    *(ushort4*)(xb + i * 4) = o;
}

// ---------------- stage 2: generate W (bf16) via MFMA ----------------
// Wave covers 128 consecutive points of one row: 4 iters x 2 interleaved
// 16-pt tiles. A-frag: m=ln (point), k=kq*8+j (+32 for *1). B-frag:
// n=nt*16+ln. C/D: col=ln (=n), row=kq*4+rg (=point) [m89/m91 layouts].
// Layer-1 h1 via sin/cos products (no trans); layer-2 via v_sin (64/point).
// 2048 blocks = 8 blocks/CU resident.
__global__ __launch_bounds__(256) void siren_w_kernel(
        const float2* __restrict__ SCrow, const float2* __restrict__ SCcol,
        const float* __restrict__ W2, const float* __restrict__ b2,
        const float* __restrict__ W3, const float* __restrict__ b3,
        unsigned short* __restrict__ Wout) {
    int lane = threadIdx.x & 63;
    int wv   = threadIdx.x >> 6;
    int ln   = lane & 15;
    int kq   = lane >> 4;

    // Preload B-frags of S*W2 (trunc bf16), S*b2, W3
    bf16x8 bfrag[2][4];
    #pragma unroll
    for (int kc = 0; kc < 2; ++kc)
        #pragma unroll
        for (int nt = 0; nt < 4; ++nt) {
            const float* src = W2 + (nt * 16 + ln) * 64 + kc * 32 + kq * 8;
            union { bf16x8 v; unsigned u[4]; } tmp;
            #pragma unroll
            for (int q = 0; q < 4; ++q)
                tmp.u[q] = pktrunc(SIN_SCALE * src[2*q], SIN_SCALE * src[2*q + 1]);
            bfrag[kc][nt] = tmp.v;
        }
    float b2v[4], w3v[4];
    #pragma unroll
    for (int nt = 0; nt < 4; ++nt) {
        b2v[nt] = SIN_SCALE * b2[nt * 16 + ln];
        w3v[nt] = W3[nt * 16 + ln];
    }
    float b3s = b3[0];

    int wid = blockIdx.x * 4 + wv;          // 0..8191 waves
    int r   = wid >> 3;                     // 8 waves per row
    int c0  = (wid & 7) * 128;

    // wave-invariant row sin/cos fragments (k = kq*8+j and 32+kq*8+j)
    const float2* rp = SCrow + (long)r * 64 + kq * 8;
    float sr0[8], cr0[8], sr1[8], cr1[8];
    #pragma unroll
    for (int j = 0; j < 8; ++j) {
        float2 t0 = rp[j];      sr0[j] = t0.x; cr0[j] = t0.y;
        float2 t1 = rp[32 + j]; sr1[j] = t1.x; cr1[j] = t1.y;
    }

    for (int it = 0; it < 4; ++it) {
        int ca = c0 + it * 32 + ln;                 // tile A point col
        const float2* fa = SCcol + (long)ca * 64 + kq * 8;
        const float2* fb = fa + 16 * 64;            // tile B: +16 cols

        // h1 = sr*cc + cr*sc  (2 VALU, 0 trans per element)
        float sa0[8], sa1[8], sb0[8], sb1[8];
        #pragma unroll
        for (int j = 0; j < 8; ++j) {
            float2 a0 = fa[j], a1 = fa[32 + j], q0 = fb[j], q1 = fb[32 + j];
            sa0[j] = fmaf(sr0[j], a0.y, cr0[j] * a0.x);
            sa1[j] = fmaf(sr1[j], a1.y, cr1[j] * a1.x);
            sb0[j] = fmaf(sr0[j], q0.y, cr0[j] * q0.x);
            sb1[j] = fmaf(sr1[j], q1.y, cr1[j] * q1.x);
        }
        union { bf16x8 v; unsigned u[4]; } a0, a1, bb0, bb1;
        #pragma unroll
        for (int q = 0; q < 4; ++q) {
            a0.u[q]  = pktrunc(sa0[2*q], sa0[2*q + 1]);
            a1.u[q]  = pktrunc(sa1[2*q], sa1[2*q + 1]);
            bb0.u[q] = pktrunc(sb0[2*q], sb0[2*q + 1]);
            bb1.u[q] = pktrunc(sb1[2*q], sb1[2*q + 1]);
        }

        f32x4 acca[4] = {}, accb[4] = {};
        #pragma unroll
        for (int nt = 0; nt < 4; ++nt) {
            acca[nt] = __builtin_amdgcn_mfma_f32_16x16x32_bf16(a0.v,  bfrag[0][nt], acca[nt], 0, 0, 0);
            accb[nt] = __builtin_amdgcn_mfma_f32_16x16x32_bf16(bb0.v, bfrag[0][nt], accb[nt], 0, 0, 0);
            acca[nt] = __builtin_amdgcn_mfma_f32_16x16x32_bf16(a1.v,  bfrag[1][nt], acca[nt], 0, 0, 0);
            accb[nt] = __builtin_amdgcn_mfma_f32_16x16x32_bf16(bb1.v, bfrag[1][nt], accb[nt], 0, 0, 0);
        }

        float pa[4], pb[4];
        #pragma unroll
        for (int rg = 0; rg < 4; ++rg) {
            float s = 0.f, t2 = 0.f;
            #pragma unroll
            for (int nt = 0; nt < 4; ++nt) {
                s  += w3v[nt] * sinrev(acca[nt][rg] + b2v[nt]);
                t2 += w3v[nt] * sinrev(accb[nt][rg] + b2v[nt]);
            }
            pa[rg] = s; pb[rg] = t2;
        }
        #pragma unroll
        for (int rg = 0; rg < 4; ++rg) {
            pa[rg] = swz_add<0x041F>(pa[rg]);  pb[rg] = swz_add<0x041F>(pb[rg]);
            pa[rg] = swz_add<0x081F>(pa[rg]);  pb[rg] = swz_add<0x081F>(pb[rg]);
            pa[rg] = swz_add<0x101F>(pa[rg]);  pb[rg] = swz_add<0x101F>(pb[rg]);
            pa[rg] = swz_add<0x201F>(pa[rg]);  pb[rg] = swz_add<0x201F>(pb[rg]);
        }

        if (ln == 0) {                       // 4 lanes store 4 points per tile (RNE)
            long p0 = (long)r * 1024 + c0 + it * 32;
            ushort4 oa, ob;
            oa.x = f2bf(pa[0] + b3s); oa.y = f2bf(pa[1] + b3s);
            oa.z = f2bf(pa[2] + b3s); oa.w = f2bf(pa[3] + b3s);
            ob.x = f2bf(pb[0] + b3s); ob.y = f2bf(pb[1] + b3s);
            ob.z = f2bf(pb[2] + b3s); ob.w = f2bf(pb[3] + b3s);
            *(ushort4*)(Wout + p0 + kq * 4)      = oa;
            *(ushort4*)(Wout + p0 + 16 + kq * 4) = ob;
        }
    }
}

// ---------------- stage 3: out = x @ W^T + bias (bf16 MFMA) ----------------
// A = x_bf16 [8192][1024] K-contig; B = W_bf16 [1024][1024] (n=r, k=c) K-contig.
// Block: 256 thr = 4 waves (2x2 of 64x64), tile 128x128, BK=64.
// DOUBLE-BUFFERED: prefetch tile t+1 (global_load_lds) before computing tile
// t; single __syncthreads per tile. LDS 64KB -> 2 blocks/CU.
// Row = 128 B = 8 chunks of 16 B; stored position p holds logical chunk
// p ^ (row&7) (staging fetches the matching global chunk; m104-legal since
// LDS dest stays linear in lane). Fragment reads hit all 8 positions ->
// 2 lanes/bank = free (m136).
__global__ __launch_bounds__(256) void gemm_kernel(
        const unsigned short* __restrict__ A,
        const unsigned short* __restrict__ B,
        const float* __restrict__ bias,
        float* __restrict__ C) {
    const int K = 1024;
    __shared__ __align__(16) unsigned short As[2][128 * 64];
    __shared__ __align__(16) unsigned short Bs[2][128 * 64];

    int tid  = threadIdx.x;
    int lane = tid & 63;
    int wv   = tid >> 6;
    int wm   = wv & 1, wn = wv >> 1;
    long Abase = (long)blockIdx.x * 128 * K;
    long Bbase = (long)blockIdx.y * 128 * K;

    int sr8 = tid >> 3;     // staging row 0..31 (+32q)
    int sl  = tid & 7;      // staging chunk slot
    int rsel = lane & 15;   // fragment m/n within 16
    int kq   = lane >> 4;   // fragment k-quad 0..3

    f32x4 acc[4][4] = {};

    // stage one 128x64 A-tile + B-tile into buffer sbuf
    auto stage = [&](int kt, int sbuf) {
        #pragma unroll
        for (int q = 0; q < 4; ++q) {
            int row = q * 32 + sr8;
            int cc  = sl ^ (row & 7);                        // global chunk to fetch
            const unsigned short* ga = A + Abase + (long)row * K + kt + cc * 8;
            const unsigned short* gb = B + Bbase + (long)row * K + kt + cc * 8;
            unsigned short* la = &As[sbuf][(q * 256 + wv * 64) * 8];  // wave-uniform base
            unsigned short* lb = &Bs[sbuf][(q * 256 + wv * 64) * 8];
            async_ld16(ga, la);
            async_ld16(gb, lb);
        }
    };

    auto compute = [&](int sbuf) {
        #pragma unroll
        for (int h = 0; h < 2; ++h) {
            bf16x8 af[4], bf[4];
            #pragma unroll
            for (int mi = 0; mi < 4; ++mi) {
                int row = wm * 64 + mi * 16 + rsel;
                int ch  = (h * 4 + kq) ^ (row & 7);
                af[mi] = *(const bf16x8*)&As[sbuf][row * 64 + ch * 8];
            }
            #pragma unroll
            for (int ni = 0; ni < 4; ++ni) {
                int row = wn * 64 + ni * 16 + rsel;
                int ch  = (h * 4 + kq) ^ (row & 7);
                bf[ni] = *(const bf16x8*)&Bs[sbuf][row * 64 + ch * 8];
            }
            #pragma unroll
            for (int mi = 0; mi < 4; ++mi)
                #pragma unroll
                for (int ni = 0; ni < 4; ++ni)
                    acc[mi][ni] = __builtin_amdgcn_mfma_f32_16x16x32_bf16(
                        af[mi], bf[ni], acc[mi][ni], 0, 0, 0);
        }
    };

    stage(0, 0);
    __syncthreads();                 // drain prologue loads
    int buf = 0;
    for (int kt = 64; kt < K; kt += 64) {
        stage(kt, buf ^ 1);          // prefetch next tile (in flight across MFMAs)
        compute(buf);
        __syncthreads();             // all ds_reads of buf done + prefetch landed
        buf ^= 1;
    }
    compute(buf);                    // last tile, no further staging

    // epilogue: C/D layout col=lane&15, row=(lane>>4)*4+reg  (m89/m91 verified)
    int row0 = blockIdx.x * 128 + wm * 64;
    int col0 = blockIdx.y * 128 + wn * 64;
    #pragma unroll
    for (int ni = 0; ni < 4; ++ni) {
        int col = col0 + ni * 16 + rsel;
        float bv = bias[col];
        #pragma unroll
        for (int mi = 0; mi < 4; ++mi) {
            int rbase = row0 + mi * 16 + kq * 4;
            #pragma unroll
            for (int r = 0; r < 4; ++r)
                C[(long)(rbase + r) * 1024 + col] = acc[mi][ni][r] + bv;
        }
    }
}

extern "C" void kernel_launch(void* const* d_in, const int* in_sizes, int n_in,
                              void* d_out, int out_size, void* d_ws, size_t ws_size,
                              hipStream_t stream) {
    const float* x    = (const float*)d_in[0];
    const float* ec   = (const float*)d_in[1];
    const float* W1   = (const float*)d_in[2];
    const float* b1   = (const float*)d_in[3];
    const float* W2   = (const float*)d_in[4];
    const float* b2   = (const float*)d_in[5];
    const float* W3   = (const float*)d_in[6];
    const float* b3   = (const float*)d_in[7];
    const float* bias = (const float*)d_in[8];
    float* out = (float*)d_out;

    unsigned short* xb = (unsigned short*)d_ws;            // 8192*1024 bf16 = 16 MB
    unsigned short* Wb = xb + (size_t)8192 * 1024;         // 1024*1024 bf16 = 2 MB
    float2* SCrow = (float2*)(Wb + (size_t)1024 * 1024);   // 1024*64 float2 = 512 KB
    float2* SCcol = SCrow + 1024 * 64;                     // 1024*64 float2 = 512 KB

    tables_kernel<<<512, 256, 0, stream>>>(ec, W1, b1, SCrow, SCcol);
    cast_kernel<<<8192, 256, 0, stream>>>((const float4*)x, xb);
    siren_w_kernel<<<2048, 256, 0, stream>>>(SCrow, SCcol, W2, b2, W3, b3, Wb);
    dim3 g(64, 8);
    gemm_kernel<<<g, 256, 0, stream>>>(xb, Wb, bias, out);
}

// Round 4
// 197.156 us; speedup vs baseline: 1.2275x; 1.2275x over previous
//
#include <hip/hip_runtime.h>
#include <hip/hip_bf16.h>

// SirenLinear: out[b,r] = sum_c x[b,c] * W[r,c] + bias[r]
//   W[r,c] = b3 + h2 . W3,  h2 = sin(30*(W2 h1 + b2)),  h1 = sin(30*(W1 e + b1))
//
// Round-10 (post-mortem r3: fma-identity siren = 82us, ALL pipes idle ->
// latency-bound on per-tile scattered VMEM loads of Zcol, not trans-bound):
//  * siren redesigned as 2-D tiled: block = 16 rows x 32 cols of W; Zrow
//    (4KB) + Zcol (8KB, chunk-XOR-swizzled) staged into LDS ONCE per block
//    via global_load_lds (pre-swizzled source, m104/m173 idiom, same as the
//    gemm staging). All h1 table reads now hit LDS at the bank-BW floor;
//    per-point VMEM traffic drops 64x. h1 reverted to proven sin(zr+zc).
//  * prep reverted to r0's merged cast+tables (proven <45us).
//  * gemm keeps r7 double-buffered LDS (1 barrier/K-tile).

typedef __attribute__((ext_vector_type(8))) short bf16x8;
typedef __attribute__((ext_vector_type(4))) float f32x4;

#define SIN_SCALE 4.77464829275686f   // 30 / (2*pi)

__device__ __forceinline__ unsigned short f2bf(float f) {
    union { float f; unsigned u; } v; v.f = f;
    unsigned r = v.u + 0x7fffu + ((v.u >> 16) & 1u);   // RNE
    return (unsigned short)(r >> 16);
}

// pack 2 floats -> 2 bf16 by truncation (cheap; RNE kept for final store)
__device__ __forceinline__ unsigned pktrunc(float a, float b) {
    union { float f; unsigned u; } x, y; x.f = a; y.f = b;
    return (x.u >> 16) | (y.u & 0xffff0000u);
}

// sin(2*pi*x) -- raw v_sin_f32, valid |x| <= 256 revs (here |x| <= ~8.3)
__device__ __forceinline__ float sinrev(float x) {
    return __builtin_amdgcn_sinf(x);
}

// butterfly add over lane^m (bitmode ds_swizzle)
template <int OFF>
__device__ __forceinline__ float swz_add(float v) {
    return v + __int_as_float(__builtin_amdgcn_ds_swizzle(__float_as_int(v), OFF));
}

__device__ __forceinline__ void async_ld16(const void* g, void* l) {
    __builtin_amdgcn_global_load_lds(
        (__attribute__((address_space(1))) void*)g,
        (__attribute__((address_space(3))) void*)l, 16, 0, 0);
}

// ---------------- prep: cast x -> bf16  +  layer-1 tables ----------------
// blocks [0,8192): cast 8M floats (one float4/thread).
// blocks [8192,8704): Zrow[r][j] = S*(W1[j,:].e(r,0)+b1[j]);
//                     Zcol[c][j] = S*(W1[j,:].(e(0,c)-e(0,0)))
__global__ __launch_bounds__(256) void prep_kernel(
        const float4* __restrict__ x, unsigned short* __restrict__ xb,
        const float* __restrict__ ec,
        const float* __restrict__ W1, const float* __restrict__ b1,
        float* __restrict__ Zrow, float* __restrict__ Zcol) {
    int b = blockIdx.x;
    if (b < 8192) {
        long i = (long)b * 256 + threadIdx.x;
        float4 v = x[i];
        ushort4 o;
        o.x = f2bf(v.x); o.y = f2bf(v.y); o.z = f2bf(v.z); o.w = f2bf(v.w);
        *(ushort4*)(xb + i * 4) = o;
    } else {
        int idx = (b - 8192) * 256 + threadIdx.x;    // 0..131071
        int j = idx & 63;
        int t = idx >> 6;                            // 0..2047
        const float* wr = W1 + j * 18;
        if (t < 1024) {
            const float* pe = ec + (long)t * 1024 * 18;   // point (r=t, c=0)
            float z = b1[j];
            #pragma unroll
            for (int i = 0; i < 18; ++i) z += wr[i] * pe[i];
            Zrow[t * 64 + j] = SIN_SCALE * z;
        } else {
            int c = t - 1024;
            const float* pe = ec + (long)c * 18;          // point (r=0, c)
            float z = 0.f;
            #pragma unroll
            for (int i = 0; i < 18; ++i) z += wr[i] * (pe[i] - ec[i]);
            Zcol[c * 64 + j] = SIN_SCALE * z;
        }
    }
}

// ---------------- stage A: generate W (bf16) via MFMA, LDS-tiled ----------
// Block (4 waves) covers a 16-row x 32-col tile of W. Zrow tile (16x64 f32,
// 4KB, linear) and Zcol tile (32x64 f32, 8KB) staged once via global_load_lds.
// Zcol LDS rows are 16 chunks of 16B; physical chunk p holds logical chunk
// p ^ (col&7) (source pre-swizzled, LDS dest linear in lane -> m104-legal).
// Compute read: lane(ln,kq) reads col cl=ct*16+ln chunks (2kq+d)^(cl&7):
// 8 distinct bank-groups x 8 lanes = LDS BW floor (vs 16-way unswizzled).
// Each wave owns 4 rows; per row: 2 col-tiles of 16. A-frag m=col(ln),
// k=kc*32+kq*8+j. C/D: col=ln (=n, h2 unit), row=kq*4+rg (=m, the col).
__global__ __launch_bounds__(256, 4) void siren_w_kernel(
        const float* __restrict__ Zrow, const float* __restrict__ Zcol,
        const float* __restrict__ W2, const float* __restrict__ b2,
        const float* __restrict__ W3, const float* __restrict__ b3,
        unsigned short* __restrict__ Wout) {
    __shared__ __align__(16) float zrow_l[16 * 64];   // 4 KB
    __shared__ __align__(16) float zcol_l[32 * 64];   // 8 KB, chunk-swizzled

    int tid  = threadIdx.x;
    int lane = tid & 63;
    int wv   = tid >> 6;
    int ln   = lane & 15;
    int kq   = lane >> 4;

    int br = blockIdx.x & 63;          // row-tile: rows [br*16, br*16+16)
    int bc = blockIdx.x >> 6;          // col-tile: cols [bc*32, bc*32+32)

    // ---- stage tables into LDS (3 x global_load_lds per thread) ----
    {
        const float* zr_src = Zrow + (long)br * 16 * 64 + (wv * 64 + lane) * 4;
        async_ld16(zr_src, zrow_l + wv * 256);        // linear, no swizzle
        #pragma unroll
        for (int half = 0; half < 2; ++half) {
            int P  = half * 256 + wv * 64 + lane;     // physical chunk 0..511
            int cr = P >> 4;                          // local col 0..31
            int lc = (P & 15) ^ (cr & 7);             // logical chunk to fetch
            const float* src = Zcol + (long)(bc * 32 + cr) * 64 + lc * 4;
            async_ld16(src, zcol_l + half * 1024 + wv * 256);
        }
    }

    // ---- preload B-frags of S*W2 (trunc bf16), S*b2, W3 (overlaps stage) ----
    bf16x8 bfrag[2][4];
    #pragma unroll
    for (int kc = 0; kc < 2; ++kc)
        #pragma unroll
        for (int nt = 0; nt < 4; ++nt) {
            const float* src = W2 + (nt * 16 + ln) * 64 + kc * 32 + kq * 8;
            union { bf16x8 v; unsigned u[4]; } tmp;
            #pragma unroll
            for (int q = 0; q < 4; ++q)
                tmp.u[q] = pktrunc(SIN_SCALE * src[2*q], SIN_SCALE * src[2*q + 1]);
            bfrag[kc][nt] = tmp.v;
        }
    float b2v[4], w3v[4];
    #pragma unroll
    for (int nt = 0; nt < 4; ++nt) {
        b2v[nt] = SIN_SCALE * b2[nt * 16 + ln];
        w3v[nt] = W3[nt * 16 + ln];
    }
    float b3s = b3[0];

    __syncthreads();                    // tables resident in LDS

    #pragma unroll
    for (int lr4 = 0; lr4 < 4; ++lr4) {
        int lr = wv * 4 + lr4;                         // local row 0..15
        const float* zb = zrow_l + lr * 64 + kq * 8;   // broadcast reads
        float zr0[8], zr1[8];
        #pragma unroll
        for (int j = 0; j < 8; ++j) { zr0[j] = zb[j]; zr1[j] = zb[32 + j]; }

        #pragma unroll
        for (int ct = 0; ct < 2; ++ct) {
            int cl = ct * 16 + ln;                     // local col 0..31
            const float* cb = zcol_l + cl * 64;
            int sw = cl & 7;
            float zc0[8], zc1[8];
            #pragma unroll
            for (int d = 0; d < 2; ++d) {
                int p0 = (((2 * kq + d)    ) ^ sw) * 4;
                int p1 = (((8 + 2 * kq + d)) ^ sw) * 4;
                #pragma unroll
                for (int e = 0; e < 4; ++e) {
                    zc0[d * 4 + e] = cb[p0 + e];
                    zc1[d * 4 + e] = cb[p1 + e];
                }
            }

            float s0[8], s1[8];
            #pragma unroll
            for (int j = 0; j < 8; ++j) {
                s0[j] = sinrev(zr0[j] + zc0[j]);
                s1[j] = sinrev(zr1[j] + zc1[j]);
            }
            union { bf16x8 v; unsigned u[4]; } a0, a1;
            #pragma unroll
            for (int q = 0; q < 4; ++q) {
                a0.u[q] = pktrunc(s0[2*q], s0[2*q + 1]);
                a1.u[q] = pktrunc(s1[2*q], s1[2*q + 1]);
            }

            f32x4 acc[4] = {};
            #pragma unroll
            for (int nt = 0; nt < 4; ++nt) {
                acc[nt] = __builtin_amdgcn_mfma_f32_16x16x32_bf16(a0.v, bfrag[0][nt], acc[nt], 0, 0, 0);
                acc[nt] = __builtin_amdgcn_mfma_f32_16x16x32_bf16(a1.v, bfrag[1][nt], acc[nt], 0, 0, 0);
            }

            float pa[4];
            #pragma unroll
            for (int rg = 0; rg < 4; ++rg) {
                float s = 0.f;
                #pragma unroll
                for (int nt = 0; nt < 4; ++nt)
                    s += w3v[nt] * sinrev(acc[nt][rg] + b2v[nt]);
                pa[rg] = s;
            }
            #pragma unroll
            for (int rg = 0; rg < 4; ++rg) {
                pa[rg] = swz_add<0x041F>(pa[rg]);
                pa[rg] = swz_add<0x081F>(pa[rg]);
                pa[rg] = swz_add<0x101F>(pa[rg]);
                pa[rg] = swz_add<0x201F>(pa[rg]);
            }

            if (ln == 0) {               // 4 lanes (kq) store 4 cols each (RNE)
                long o = (long)(br * 16 + lr) * 1024 + bc * 32 + ct * 16 + kq * 4;
                ushort4 oa;
                oa.x = f2bf(pa[0] + b3s); oa.y = f2bf(pa[1] + b3s);
                oa.z = f2bf(pa[2] + b3s); oa.w = f2bf(pa[3] + b3s);
                *(ushort4*)(Wout + o) = oa;
            }
        }
    }
}

// ---------------- stage B: out = x @ W^T + bias (bf16 MFMA) ----------------
// A = x_bf16 [8192][1024] K-contig; B = W_bf16 [1024][1024] (n=r, k=c) K-contig.
// Block: 256 thr = 4 waves (2x2 of 64x64), tile 128x128, BK=64.
// DOUBLE-BUFFERED: prefetch tile t+1 (global_load_lds) before computing tile
// t; single __syncthreads per tile. LDS 64KB -> 2 blocks/CU.
// Row = 128 B = 8 chunks of 16 B; stored position p holds logical chunk
// p ^ (row&7). Fragment reads hit all 8 positions -> 2 lanes/bank = free.
__global__ __launch_bounds__(256) void gemm_kernel(
        const unsigned short* __restrict__ A,
        const unsigned short* __restrict__ B,
        const float* __restrict__ bias,
        float* __restrict__ C) {
    const int K = 1024;
    __shared__ __align__(16) unsigned short As[2][128 * 64];
    __shared__ __align__(16) unsigned short Bs[2][128 * 64];

    int tid  = threadIdx.x;
    int lane = tid & 63;
    int wv   = tid >> 6;
    int wm   = wv & 1, wn = wv >> 1;
    long Abase = (long)blockIdx.x * 128 * K;
    long Bbase = (long)blockIdx.y * 128 * K;

    int sr8 = tid >> 3;     // staging row 0..31 (+32q)
    int sl  = tid & 7;      // staging chunk slot
    int rsel = lane & 15;   // fragment m/n within 16
    int kq   = lane >> 4;   // fragment k-quad 0..3

    f32x4 acc[4][4] = {};

    auto stage = [&](int kt, int sbuf) {
        #pragma unroll
        for (int q = 0; q < 4; ++q) {
            int row = q * 32 + sr8;
            int cc  = sl ^ (row & 7);                        // global chunk to fetch
            const unsigned short* ga = A + Abase + (long)row * K + kt + cc * 8;
            const unsigned short* gb = B + Bbase + (long)row * K + kt + cc * 8;
            unsigned short* la = &As[sbuf][(q * 256 + wv * 64) * 8];  // wave-uniform base
            unsigned short* lb = &Bs[sbuf][(q * 256 + wv * 64) * 8];
            async_ld16(ga, la);
            async_ld16(gb, lb);
        }
    };

    auto compute = [&](int sbuf) {
        #pragma unroll
        for (int h = 0; h < 2; ++h) {
            bf16x8 af[4], bf[4];
            #pragma unroll
            for (int mi = 0; mi < 4; ++mi) {
                int row = wm * 64 + mi * 16 + rsel;
                int ch  = (h * 4 + kq) ^ (row & 7);
                af[mi] = *(const bf16x8*)&As[sbuf][row * 64 + ch * 8];
            }
            #pragma unroll
            for (int ni = 0; ni < 4; ++ni) {
                int row = wn * 64 + ni * 16 + rsel;
                int ch  = (h * 4 + kq) ^ (row & 7);
                bf[ni] = *(const bf16x8*)&Bs[sbuf][row * 64 + ch * 8];
            }
            #pragma unroll
            for (int mi = 0; mi < 4; ++mi)
                #pragma unroll
                for (int ni = 0; ni < 4; ++ni)
                    acc[mi][ni] = __builtin_amdgcn_mfma_f32_16x16x32_bf16(
                        af[mi], bf[ni], acc[mi][ni], 0, 0, 0);
        }
    };

    stage(0, 0);
    __syncthreads();                 // drain prologue loads
    int buf = 0;
    for (int kt = 64; kt < K; kt += 64) {
        stage(kt, buf ^ 1);          // prefetch next tile (in flight across MFMAs)
        compute(buf);
        __syncthreads();             // all ds_reads of buf done + prefetch landed
        buf ^= 1;
    }
    compute(buf);                    // last tile, no further staging

    // epilogue: C/D layout col=lane&15, row=(lane>>4)*4+reg  (m89/m91 verified)
    int row0 = blockIdx.x * 128 + wm * 64;
    int col0 = blockIdx.y * 128 + wn * 64;
    #pragma unroll
    for (int ni = 0; ni < 4; ++ni) {
        int col = col0 + ni * 16 + rsel;
        float bv = bias[col];
        #pragma unroll
        for (int mi = 0; mi < 4; ++mi) {
            int rbase = row0 + mi * 16 + kq * 4;
            #pragma unroll
            for (int r = 0; r < 4; ++r)
                C[(long)(rbase + r) * 1024 + col] = acc[mi][ni][r] + bv;
        }
    }
}

extern "C" void kernel_launch(void* const* d_in, const int* in_sizes, int n_in,
                              void* d_out, int out_size, void* d_ws, size_t ws_size,
                              hipStream_t stream) {
    const float* x    = (const float*)d_in[0];
    const float* ec   = (const float*)d_in[1];
    const float* W1   = (const float*)d_in[2];
    const float* b1   = (const float*)d_in[3];
    const float* W2   = (const float*)d_in[4];
    const float* b2   = (const float*)d_in[5];
    const float* W3   = (const float*)d_in[6];
    const float* b3   = (const float*)d_in[7];
    const float* bias = (const float*)d_in[8];
    float* out = (float*)d_out;

    unsigned short* xb = (unsigned short*)d_ws;            // 8192*1024 bf16 = 16 MB
    unsigned short* Wb = xb + (size_t)8192 * 1024;         // 1024*1024 bf16 = 2 MB
    float* Zrow = (float*)(Wb + (size_t)1024 * 1024);      // 1024*64 f32 = 256 KB
    float* Zcol = Zrow + 1024 * 64;                        // 1024*64 f32 = 256 KB

    prep_kernel<<<8704, 256, 0, stream>>>((const float4*)x, xb, ec, W1, b1, Zrow, Zcol);
    siren_w_kernel<<<2048, 256, 0, stream>>>(Zrow, Zcol, W2, b2, W3, b3, Wb);
    dim3 g(64, 8);
    gemm_kernel<<<g, 256, 0, stream>>>(xb, Wb, bias, out);
}

// Round 5
// 192.428 us; speedup vs baseline: 1.2577x; 1.0246x over previous
//
#include <hip/hip_runtime.h>
#include <hip/hip_bf16.h>

// SirenLinear: out[b,r] = sum_c x[b,c] * W[r,c] + bias[r]
//   W[r,c] = b3 + h2 . W3,  h2 = sin(30*(W2 h1 + b2)),  h1 = sin(30*(W1 e + b1))
//
// Round-11 (post-mortem r4: siren ~38us vs ~8us issue floor, gemm ~28, prep
// ~13, fixed ~115. Siren is issue/latency-bound; its reduce tail is 16
// ds_swizzle chains on the critical path):
//  * reduce tail: ds_swizzle butterfly -> DPP row_ror rotate-and-add
//    (pure VALU, no DS latency, no lgkmcnt).
//  * cast re-fused into siren launch (1-in-5 of 10240 blocks): r1/r2 proved
//    cast hides completely under siren compute (fused == siren alone).
//  * tables standalone (512 blocks, ~2us, siren dependency).
//  * gemm untouched (r7 double-buffered, 1 barrier/K-tile).

typedef __attribute__((ext_vector_type(8))) short bf16x8;
typedef __attribute__((ext_vector_type(4))) float f32x4;

#define SIN_SCALE 4.77464829275686f   // 30 / (2*pi)

__device__ __forceinline__ unsigned short f2bf(float f) {
    union { float f; unsigned u; } v; v.f = f;
    unsigned r = v.u + 0x7fffu + ((v.u >> 16) & 1u);   // RNE
    return (unsigned short)(r >> 16);
}

// pack 2 floats -> 2 bf16 by truncation (cheap; RNE kept for final store)
__device__ __forceinline__ unsigned pktrunc(float a, float b) {
    union { float f; unsigned u; } x, y; x.f = a; y.f = b;
    return (x.u >> 16) | (y.u & 0xffff0000u);
}

// sin(2*pi*x) -- raw v_sin_f32, valid |x| <= 256 revs (here |x| <= ~8.3)
__device__ __forceinline__ float sinrev(float x) {
    return __builtin_amdgcn_sinf(x);
}

// v += rotate_within_16lane_row(v, N)  -- DPP row_ror, pure VALU
template <int CTRL>
__device__ __forceinline__ float dpp_add(float v) {
    int r = __builtin_amdgcn_update_dpp(0, __float_as_int(v), CTRL, 0xf, 0xf, true);
    return v + __int_as_float(r);
}
// full 16-lane-row sum in every lane: ror 1,2,4,8
__device__ __forceinline__ float rowsum16(float v) {
    v = dpp_add<0x121>(v);   // row_ror:1
    v = dpp_add<0x122>(v);   // row_ror:2
    v = dpp_add<0x124>(v);   // row_ror:4
    v = dpp_add<0x128>(v);   // row_ror:8
    return v;
}

__device__ __forceinline__ void async_ld16(const void* g, void* l) {
    __builtin_amdgcn_global_load_lds(
        (__attribute__((address_space(1))) void*)g,
        (__attribute__((address_space(3))) void*)l, 16, 0, 0);
}

// ---------------- stage 0: layer-1 separable tables ----------------
// Zrow[r][j] = S*(W1[j,:].e(r,0)+b1[j]);  Zcol[c][j] = S*(W1[j,:].(e(0,c)-e(0,0)))
__global__ __launch_bounds__(256) void tables_kernel(
        const float* __restrict__ ec,
        const float* __restrict__ W1, const float* __restrict__ b1,
        float* __restrict__ Zrow, float* __restrict__ Zcol) {
    int idx = blockIdx.x * 256 + threadIdx.x;    // 0..131071
    int j = idx & 63;
    int t = idx >> 6;                            // 0..2047
    const float* wr = W1 + j * 18;
    if (t < 1024) {
        const float* pe = ec + (long)t * 1024 * 18;   // point (r=t, c=0)
        float z = b1[j];
        #pragma unroll
        for (int i = 0; i < 18; ++i) z += wr[i] * pe[i];
        Zrow[t * 64 + j] = SIN_SCALE * z;
    } else {
        int c = t - 1024;
        const float* pe = ec + (long)c * 18;          // point (r=0, c)
        float z = 0.f;
        #pragma unroll
        for (int i = 0; i < 18; ++i) z += wr[i] * (pe[i] - ec[i]);
        Zcol[c * 64 + j] = SIN_SCALE * z;
    }
}

// ---------------- stage 1: [x cast -> bf16] || [generate W, LDS-tiled] -----
// 10240 blocks; blockIdx.x % 5 == 0 -> siren (2048), else cast (8192).
// Cast blocks are pure streaming and hide under siren compute (r1/r2 data).
//
// siren: block (4 waves) covers 16 rows x 32 cols of W. Zrow tile (4KB,
// linear) + Zcol tile (8KB, chunk-XOR-swizzled) staged once via
// global_load_lds (pre-swizzled source, m104/m173). Wave owns 4 rows; per
// row 2 col-tiles of 16. A-frag m=col(ln), k=kc*32+kq*8+j. C/D: col=ln
// (=n, h2 unit), row=kq*4+rg (=m, the col) [m89/m91]. Final 64-unit dot
// reduced with DPP rowsum16 (VALU) instead of ds_swizzle (DS).
__global__ __launch_bounds__(256, 4) void fused_cast_siren(
        const float4* __restrict__ x, unsigned short* __restrict__ xb,
        const float* __restrict__ Zrow, const float* __restrict__ Zcol,
        const float* __restrict__ W2, const float* __restrict__ b2,
        const float* __restrict__ W3, const float* __restrict__ b3,
        unsigned short* __restrict__ Wout) {
    __shared__ __align__(16) float zrow_l[16 * 64];   // 4 KB
    __shared__ __align__(16) float zcol_l[32 * 64];   // 8 KB, chunk-swizzled

    int bid = blockIdx.x;
    int sb  = bid / 5;
    if (bid - sb * 5 != 0) {
        // ---- cast path: one float4 -> ushort4 per thread ----
        int cb = bid - sb - 1;                       // 0..8191
        long i = (long)cb * 256 + threadIdx.x;
        float4 v = x[i];
        ushort4 o;
        o.x = f2bf(v.x); o.y = f2bf(v.y); o.z = f2bf(v.z); o.w = f2bf(v.w);
        *(ushort4*)(xb + i * 4) = o;
        return;
    }

    // ---- siren path: sb in 0..2047 ----
    int tid  = threadIdx.x;
    int lane = tid & 63;
    int wv   = tid >> 6;
    int ln   = lane & 15;
    int kq   = lane >> 4;

    int br = sb & 63;                  // row-tile: rows [br*16, br*16+16)
    int bc = sb >> 6;                  // col-tile: cols [bc*32, bc*32+32)

    // ---- stage tables into LDS (3 x global_load_lds per thread) ----
    {
        const float* zr_src = Zrow + (long)br * 16 * 64 + (wv * 64 + lane) * 4;
        async_ld16(zr_src, zrow_l + wv * 256);        // linear, no swizzle
        #pragma unroll
        for (int half = 0; half < 2; ++half) {
            int P  = half * 256 + wv * 64 + lane;     // physical chunk 0..511
            int cr = P >> 4;                          // local col 0..31
            int lc = (P & 15) ^ (cr & 7);             // logical chunk to fetch
            const float* src = Zcol + (long)(bc * 32 + cr) * 64 + lc * 4;
            async_ld16(src, zcol_l + half * 1024 + wv * 256);
        }
    }

    // ---- preload B-frags of S*W2 (trunc bf16), S*b2, W3 (overlaps stage) ----
    bf16x8 bfrag[2][4];
    #pragma unroll
    for (int kc = 0; kc < 2; ++kc)
        #pragma unroll
        for (int nt = 0; nt < 4; ++nt) {
            const float* src = W2 + (nt * 16 + ln) * 64 + kc * 32 + kq * 8;
            union { bf16x8 v; unsigned u[4]; } tmp;
            #pragma unroll
            for (int q = 0; q < 4; ++q)
                tmp.u[q] = pktrunc(SIN_SCALE * src[2*q], SIN_SCALE * src[2*q + 1]);
            bfrag[kc][nt] = tmp.v;
        }
    float b2v[4], w3v[4];
    #pragma unroll
    for (int nt = 0; nt < 4; ++nt) {
        b2v[nt] = SIN_SCALE * b2[nt * 16 + ln];
        w3v[nt] = W3[nt * 16 + ln];
    }
    float b3s = b3[0];

    __syncthreads();                    // tables resident in LDS

    #pragma unroll
    for (int lr4 = 0; lr4 < 4; ++lr4) {
        int lr = wv * 4 + lr4;                         // local row 0..15
        const float* zb = zrow_l + lr * 64 + kq * 8;   // broadcast reads
        float zr0[8], zr1[8];
        #pragma unroll
        for (int j = 0; j < 8; ++j) { zr0[j] = zb[j]; zr1[j] = zb[32 + j]; }

        #pragma unroll
        for (int ct = 0; ct < 2; ++ct) {
            int cl = ct * 16 + ln;                     // local col 0..31
            const float* cb = zcol_l + cl * 64;
            int sw = cl & 7;
            float zc0[8], zc1[8];
            #pragma unroll
            for (int d = 0; d < 2; ++d) {
                int p0 = (((2 * kq + d)    ) ^ sw) * 4;
                int p1 = (((8 + 2 * kq + d)) ^ sw) * 4;
                #pragma unroll
                for (int e = 0; e < 4; ++e) {
                    zc0[d * 4 + e] = cb[p0 + e];
                    zc1[d * 4 + e] = cb[p1 + e];
                }
            }

            float s0[8], s1[8];
            #pragma unroll
            for (int j = 0; j < 8; ++j) {
                s0[j] = sinrev(zr0[j] + zc0[j]);
                s1[j] = sinrev(zr1[j] + zc1[j]);
            }
            union { bf16x8 v; unsigned u[4]; } a0, a1;
            #pragma unroll
            for (int q = 0; q < 4; ++q) {
                a0.u[q] = pktrunc(s0[2*q], s0[2*q + 1]);
                a1.u[q] = pktrunc(s1[2*q], s1[2*q + 1]);
            }

            f32x4 acc[4] = {};
            #pragma unroll
            for (int nt = 0; nt < 4; ++nt) {
                acc[nt] = __builtin_amdgcn_mfma_f32_16x16x32_bf16(a0.v, bfrag[0][nt], acc[nt], 0, 0, 0);
                acc[nt] = __builtin_amdgcn_mfma_f32_16x16x32_bf16(a1.v, bfrag[1][nt], acc[nt], 0, 0, 0);
            }

            float pa[4];
            #pragma unroll
            for (int rg = 0; rg < 4; ++rg) {
                float s = 0.f;
                #pragma unroll
                for (int nt = 0; nt < 4; ++nt)
                    s += w3v[nt] * sinrev(acc[nt][rg] + b2v[nt]);
                pa[rg] = rowsum16(s);                  // DPP, all-lane result
            }

            if (ln == 0) {               // 4 lanes (kq) store 4 cols each (RNE)
                long o = (long)(br * 16 + lr) * 1024 + bc * 32 + ct * 16 + kq * 4;
                ushort4 oa;
                oa.x = f2bf(pa[0] + b3s); oa.y = f2bf(pa[1] + b3s);
                oa.z = f2bf(pa[2] + b3s); oa.w = f2bf(pa[3] + b3s);
                *(ushort4*)(Wout + o) = oa;
            }
        }
    }
}

// ---------------- stage 2: out = x @ W^T + bias (bf16 MFMA) ----------------
// A = x_bf16 [8192][1024] K-contig; B = W_bf16 [1024][1024] (n=r, k=c) K-contig.
// Block: 256 thr = 4 waves (2x2 of 64x64), tile 128x128, BK=64.
// DOUBLE-BUFFERED: prefetch tile t+1 (global_load_lds) before computing tile
// t; single __syncthreads per tile. LDS 64KB -> 2 blocks/CU.
// Row = 128 B = 8 chunks of 16 B; stored position p holds logical chunk
// p ^ (row&7). Fragment reads hit all 8 positions -> 2 lanes/bank = free.
__global__ __launch_bounds__(256) void gemm_kernel(
        const unsigned short* __restrict__ A,
        const unsigned short* __restrict__ B,
        const float* __restrict__ bias,
        float* __restrict__ C) {
    const int K = 1024;
    __shared__ __align__(16) unsigned short As[2][128 * 64];
    __shared__ __align__(16) unsigned short Bs[2][128 * 64];

    int tid  = threadIdx.x;
    int lane = tid & 63;
    int wv   = tid >> 6;
    int wm   = wv & 1, wn = wv >> 1;
    long Abase = (long)blockIdx.x * 128 * K;
    long Bbase = (long)blockIdx.y * 128 * K;

    int sr8 = tid >> 3;     // staging row 0..31 (+32q)
    int sl  = tid & 7;      // staging chunk slot
    int rsel = lane & 15;   // fragment m/n within 16
    int kq   = lane >> 4;   // fragment k-quad 0..3

    f32x4 acc[4][4] = {};

    auto stage = [&](int kt, int sbuf) {
        #pragma unroll
        for (int q = 0; q < 4; ++q) {
            int row = q * 32 + sr8;
            int cc  = sl ^ (row & 7);                        // global chunk to fetch
            const unsigned short* ga = A + Abase + (long)row * K + kt + cc * 8;
            const unsigned short* gb = B + Bbase + (long)row * K + kt + cc * 8;
            unsigned short* la = &As[sbuf][(q * 256 + wv * 64) * 8];  // wave-uniform base
            unsigned short* lb = &Bs[sbuf][(q * 256 + wv * 64) * 8];
            async_ld16(ga, la);
            async_ld16(gb, lb);
        }
    };

    auto compute = [&](int sbuf) {
        #pragma unroll
        for (int h = 0; h < 2; ++h) {
            bf16x8 af[4], bf[4];
            #pragma unroll
            for (int mi = 0; mi < 4; ++mi) {
                int row = wm * 64 + mi * 16 + rsel;
                int ch  = (h * 4 + kq) ^ (row & 7);
                af[mi] = *(const bf16x8*)&As[sbuf][row * 64 + ch * 8];
            }
            #pragma unroll
            for (int ni = 0; ni < 4; ++ni) {
                int row = wn * 64 + ni * 16 + rsel;
                int ch  = (h * 4 + kq) ^ (row & 7);
                bf[ni] = *(const bf16x8*)&Bs[sbuf][row * 64 + ch * 8];
            }
            #pragma unroll
            for (int mi = 0; mi < 4; ++mi)
                #pragma unroll
                for (int ni = 0; ni < 4; ++ni)
                    acc[mi][ni] = __builtin_amdgcn_mfma_f32_16x16x32_bf16(
                        af[mi], bf[ni], acc[mi][ni], 0, 0, 0);
        }
    };

    stage(0, 0);
    __syncthreads();                 // drain prologue loads
    int buf = 0;
    for (int kt = 64; kt < K; kt += 64) {
        stage(kt, buf ^ 1);          // prefetch next tile (in flight across MFMAs)
        compute(buf);
        __syncthreads();             // all ds_reads of buf done + prefetch landed
        buf ^= 1;
    }
    compute(buf);                    // last tile, no further staging

    // epilogue: C/D layout col=lane&15, row=(lane>>4)*4+reg  (m89/m91 verified)
    int row0 = blockIdx.x * 128 + wm * 64;
    int col0 = blockIdx.y * 128 + wn * 64;
    #pragma unroll
    for (int ni = 0; ni < 4; ++ni) {
        int col = col0 + ni * 16 + rsel;
        float bv = bias[col];
        #pragma unroll
        for (int mi = 0; mi < 4; ++mi) {
            int rbase = row0 + mi * 16 + kq * 4;
            #pragma unroll
            for (int r = 0; r < 4; ++r)
                C[(long)(rbase + r) * 1024 + col] = acc[mi][ni][r] + bv;
        }
    }
}

extern "C" void kernel_launch(void* const* d_in, const int* in_sizes, int n_in,
                              void* d_out, int out_size, void* d_ws, size_t ws_size,
                              hipStream_t stream) {
    const float* x    = (const float*)d_in[0];
    const float* ec   = (const float*)d_in[1];
    const float* W1   = (const float*)d_in[2];
    const float* b1   = (const float*)d_in[3];
    const float* W2   = (const float*)d_in[4];
    const float* b2   = (const float*)d_in[5];
    const float* W3   = (const float*)d_in[6];
    const float* b3   = (const float*)d_in[7];
    const float* bias = (const float*)d_in[8];
    float* out = (float*)d_out;

    unsigned short* xb = (unsigned short*)d_ws;            // 8192*1024 bf16 = 16 MB
    unsigned short* Wb = xb + (size_t)8192 * 1024;         // 1024*1024 bf16 = 2 MB
    float* Zrow = (float*)(Wb + (size_t)1024 * 1024);      // 1024*64 f32 = 256 KB
    float* Zcol = Zrow + 1024 * 64;                        // 1024*64 f32 = 256 KB

    tables_kernel<<<512, 256, 0, stream>>>(ec, W1, b1, Zrow, Zcol);
    fused_cast_siren<<<10240, 256, 0, stream>>>((const float4*)x, xb, Zrow, Zcol,
                                                W2, b2, W3, b3, Wb);
    dim3 g(64, 8);
    gemm_kernel<<<g, 256, 0, stream>>>(xb, Wb, bias, out);
}